// Round 8
// baseline (227.734 us; speedup 1.0000x reference)
//
#include <hip/hip_runtime.h>
#include <stdint.h>

typedef uint16_t u16;
typedef u16   u16x4  __attribute__((ext_vector_type(4)));
typedef u16   u16x8  __attribute__((ext_vector_type(8)));
typedef __bf16 bf16x8 __attribute__((ext_vector_type(8)));
typedef float f32x4  __attribute__((ext_vector_type(4)));

__device__ __forceinline__ float b2f(u16 x) {
    union { uint32_t u; float f; } c; c.u = ((uint32_t)x) << 16; return c.f;
}
__device__ __forceinline__ u16 f2b(float f) {
    union { float f; uint32_t u; } c; c.f = f;
    uint32_t r = c.u + 0x7FFFu + ((c.u >> 16) & 1u);
    return (u16)(r >> 16);
}
__device__ __forceinline__ float silu_f(float x) { return x / (1.f + __expf(-x)); }
__device__ __forceinline__ float softplus_f(float x) {
    return fmaxf(x, 0.f) + __logf(1.f + __expf(-fabsf(x)));
}

__device__ __forceinline__ void gload16(const u16* g, u16* l) {
    __builtin_amdgcn_global_load_lds(
        (const __attribute__((address_space(1))) void*)(g),
        (__attribute__((address_space(3))) void*)(l), 16, 0, 0);
}

// per-block dtype flag: 1 = f32 inputs, 0 = bf16. Contains barriers; call first.
__device__ __forceinline__ int dtype_flag_block(const u16* __restrict__ xraw) {
    __shared__ int bad;
    if (threadIdx.x == 0) bad = 0;
    __syncthreads();
    float v = b2f(xraw[threadIdx.x]);
    if (!(fabsf(v) < 1000.f)) atomicAdd(&bad, 1);   // NaN-safe
    __syncthreads();
    return bad;
}

// ---------------- unified input canonicalization (14 segments) ----------------
// seg 13: zero-fill of the f32 x_dbl atomic accumulator (must precede gemm EPI=3).
struct CvtArgs {
    const void* s[14];
    u16* d[14];
    int cum[15];
    int total;
};
__global__ __launch_bounds__(256) void cvt_all_k(CvtArgs a, const u16* __restrict__ xraw)
{
    int flag = dtype_flag_block(xraw);
    int u4 = blockIdx.x * 256 + threadIdx.x;
    if (u4 >= a.total) return;
    int seg = 0;
    while (u4 >= a.cum[seg + 1]) seg++;
    int local = u4 - a.cum[seg];
    const void* s = a.s[seg];
    u16x4 o;
    if (s == nullptr) {
        o[0] = o[1] = o[2] = o[3] = 0;
    } else if (flag) {
        f32x4 vv = ((const f32x4*)s)[local];
        for (int e = 0; e < 4; e++) o[e] = f2b(vv[e]);
    } else {
        o = ((const u16x4*)s)[local];
    }
    *(u16x4*)(a.d[seg] + (size_t)local * 4) = o;
}

// ---------------- MFMA NT GEMM core: C[m,n] = sum_k A[m,k]*B[n,k] ----------------
// 128(M) x TN(N) tile, BK=64, 4 waves (2x2), swizzled LDS slots.
// Async global_load_lds staging. EPI 0: bf16 store. 2: f32 partial at
// Cf + z*zslab. 3: f32 atomicAdd into Cf (split-K w/o slabs; Cf pre-zeroed).
// Kc multiple of 64.
// NOTE r2: TN=128 regressed (fewer resident blocks -> less cross-block
// overlap at these shapes). Keep TN=64.
template<int EPI, int TN>
__device__ __forceinline__ void gemm_core(
    int bx, int by, int bz,
    const u16* __restrict__ A, const u16* __restrict__ B,
    int Kc, int lda, int ldb,
    u16* __restrict__ Cb, float* __restrict__ Cf, int ldc, int ncols,
    size_t zslab)
{
    constexpr int NJ = TN / 32;
    constexpr int BT = TN / 32;
    __shared__ __align__(16) u16 lA[128 * 64];
    __shared__ __align__(16) u16 lB[TN * 64];
    const int tid  = threadIdx.x;
    const int wave = tid >> 6, lane = tid & 63;
    const int quad = lane >> 4, l16 = lane & 15;
    const int wm = wave & 1, wn = wave >> 1;
    const int row0 = by * 128, col0 = bx * TN;
    const int kbeg = bz * Kc;

    f32x4 acc[4][NJ];
    const f32x4 zf = {0.f, 0.f, 0.f, 0.f};
    for (int i = 0; i < 4; i++) for (int j = 0; j < NJ; j++) acc[i][j] = zf;

    // chunk c: 16B at lX[c*8]; row r=c>>3, slot s=c&7 holds k-group
    // q=(s-(r>>1))&7 (bank swizzle).
    const u16* Ap[4]; const u16* Bp[BT];
    int lbaseA[4], lbaseB[BT];
    for (int t = 0; t < 4; t++) {
        int c = t * 256 + tid;
        int r = c >> 3, s = c & 7;
        int q = (s - (r >> 1)) & 7;
        Ap[t] = A + (size_t)(row0 + r) * lda + q * 8 + kbeg;
        lbaseA[t] = (t * 256 + wave * 64) * 8;
    }
    for (int t = 0; t < BT; t++) {
        int c = t * 256 + tid;
        int r = c >> 3, s = c & 7;
        int q = (s - (r >> 1)) & 7;
        Bp[t] = B + (size_t)(col0 + r) * ldb + q * 8 + kbeg;
        lbaseB[t] = (t * 256 + wave * 64) * 8;
    }

    for (int k0 = 0; k0 < Kc; k0 += 64) {
        for (int t = 0; t < 4; t++) gload16(Ap[t] + k0, &lA[lbaseA[t]]);
        for (int t = 0; t < BT; t++) gload16(Bp[t] + k0, &lB[lbaseB[t]]);
        __syncthreads();
        for (int half = 0; half < 2; half++) {
            bf16x8 af[4], bfr[NJ];
            for (int i = 0; i < 4; i++) {
                int r = wm * 64 + i * 16 + l16;
                int s = (half * 4 + quad + (r >> 1)) & 7;
                af[i] = *(const bf16x8*)&lA[r * 64 + s * 8];
            }
            for (int j = 0; j < NJ; j++) {
                int r = wn * (TN / 2) + j * 16 + l16;
                int s = (half * 4 + quad + (r >> 1)) & 7;
                bfr[j] = *(const bf16x8*)&lB[r * 64 + s * 8];
            }
            for (int i = 0; i < 4; i++)
                for (int j = 0; j < NJ; j++)
                    acc[i][j] = __builtin_amdgcn_mfma_f32_16x16x32_bf16(af[i], bfr[j], acc[i][j], 0, 0, 0);
        }
        __syncthreads();
    }

    float* dstf = (EPI == 2) ? (Cf + (size_t)bz * zslab) : Cf;
    for (int i = 0; i < 4; i++) {
        int mb = row0 + wm * 64 + i * 16 + quad * 4;
        for (int j = 0; j < NJ; j++) {
            int n = col0 + wn * (TN / 2) + j * 16 + l16;
            if (n >= ncols) continue;
            if (EPI == 0) {
                for (int v = 0; v < 4; v++)
                    Cb[(size_t)(mb + v) * ldc + n] = f2b(acc[i][j][v]);
            } else if (EPI == 2) {
                for (int v = 0; v < 4; v++)
                    dstf[(size_t)(mb + v) * ldc + n] = acc[i][j][v];
            } else {
                for (int v = 0; v < 4; v++)
                    atomicAdd(&dstf[(size_t)(mb + v) * ldc + n], acc[i][j][v]);
            }
        }
    }
}

template<int EPI, int TN>
__global__ __launch_bounds__(256) void gemm_bt(
    const u16* __restrict__ A, const u16* __restrict__ B,
    int Kc, int lda, int ldb,
    u16* __restrict__ Cb, float* __restrict__ Cf, int ldc, int ncols,
    size_t zslab)
{
    gemm_core<EPI, TN>(blockIdx.x, blockIdx.y, blockIdx.z,
                       A, B, Kc, lda, ldb, Cb, Cf, ldc, ncols, zslab);
}

// ---------------- depthwise causal conv(4) + bias + SiLU ----------------
__global__ __launch_bounds__(256) void conv_silu_k(
    const u16* __restrict__ xr, const u16* __restrict__ cw,
    const u16* __restrict__ cb, u16* __restrict__ u)
{
    int tid = threadIdx.x;
    int bl  = blockIdx.x;       // b*1024 + l
    int l   = bl & 1023;
    int d0  = tid * 8;
    float acc[8];
    u16x8 bias = *(const u16x8*)&cb[d0];
    for (int j = 0; j < 8; j++) acc[j] = b2f(bias[j]);
    union { u16x8 v[4]; u16 s[32]; } wb;
    for (int t = 0; t < 4; t++) wb.v[t] = *(const u16x8*)&cw[d0 * 4 + t * 8];
    for (int t = 0; t < 4; t++) {
        int ls = l - 3 + t;
        if (ls < 0) continue;
        u16x8 xv = *(const u16x8*)&xr[(size_t)(bl - 3 + t) * 4096 + d0];
        for (int j = 0; j < 8; j++) acc[j] += b2f(xv[j]) * b2f(wb.s[j * 4 + t]);
    }
    u16x8 o;
    for (int j = 0; j < 8; j++) o[j] = f2b(silu_f(acc[j]));
    *(u16x8*)&u[(size_t)bl * 2048 + d0] = o;
}

// ---------------- fused: scan (blocks 0..1023) + qkv (1024..1519) ----------------
// r8: r6 structure (best measured), but x_dbl now read from the f32 atomic
// accumulator (redc_k eliminated). lA staged via convert+ds_write (same
// swizzled layout as gload16 path); Bs/Cs read f32 directly (no bf16
// roundtrip -> closer to reference numerics).
// LDS 24KB => 6 blocks/CU. u16 units: lA[0,2048) | lB[2048,10240) |
// Bs[10240,11264) | Cs[11264,12288); phase2: dls f32 aliases [0,8192).
__global__ __launch_bounds__(256) void scan_qkv_k(
    const u16* __restrict__ u, const u16* __restrict__ xr,
    const float* __restrict__ xdf, const u16* __restrict__ Wdt,
    const u16* __restrict__ bdt,
    const u16* __restrict__ latent, const u16* __restrict__ Alog,
    const u16* __restrict__ Dp, u16* __restrict__ yg,
    const u16* __restrict__ Wc, u16* __restrict__ q, u16* __restrict__ k,
    u16* __restrict__ v)
{
    __shared__ __align__(16) u16 lsh[12288];    // 24KB
    int tid = threadIdx.x;
    int bid = blockIdx.x;
    if (bid < 1024) {
        u16* lA = lsh;
        u16* lB = lsh + 2048;
        float* dls = (float*)lsh;               // [32][128], aliases lA+lB
        float (*Bs)[16] = (float(*)[16])(lsh + 10240);
        float (*Cs)[16] = (float(*)[16])(lsh + 11264);
        const int wave = tid >> 6, lane = tid & 63;
        const int quad = lane >> 4, l16 = lane & 15;
        const int nh = lane >> 5;
        int dblk = bid & 15, bg = bid >> 4;      // bg = b*32+g
        const int d = dblk * 128 + wave * 32 + (lane & 31);
        const int rowb = bg * 32;

        // stage A = f2b(xdf[bg's 32 rows][0:64]) swizzled, via ds_write
        {
            int r = tid >> 3, s = tid & 7;
            int qg = (s - (r >> 1)) & 7;
            const float* xp = &xdf[(size_t)(rowb + r) * 128 + qg * 8];
            f32x4 v0 = *(const f32x4*)xp;
            f32x4 v1 = *(const f32x4*)(xp + 4);
            u16x8 o;
            for (int e = 0; e < 4; e++) { o[e] = f2b(v0[e]); o[4 + e] = f2b(v1[e]); }
            *(u16x8*)&lA[tid * 8] = o;
        }
        // stage B = Wdt rows [dblk*128, +128) (4 chunks/thread)
        for (int t = 0; t < 4; t++) {
            int c = t * 256 + tid;
            int r = c >> 3, s = c & 7;
            int qg = (s - (r >> 1)) & 7;
            gload16(&Wdt[(size_t)(dblk * 128 + r) * 64 + qg * 8],
                    &lB[(t * 256 + wave * 64) * 8]);
        }
        // B/C tiles from xdf cols 64..96 (f32 direct)
        for (int idx = tid; idx < 512; idx += 256) {
            int p = idx >> 4, n = idx & 15;
            const float* xp = &xdf[(size_t)(rowb + p) * 128];
            Bs[p][n] = xp[64 + n];
            Cs[p][n] = xp[80 + n];
        }
        __syncthreads();

        // delta MFMA: C[32p x 128d], wave covers 32 d-cols: 2 p-sub x 2 d-sub
        f32x4 dacc[2][2];
        const f32x4 zf = {0.f, 0.f, 0.f, 0.f};
        for (int i = 0; i < 2; i++) for (int j = 0; j < 2; j++) dacc[i][j] = zf;
        for (int half = 0; half < 2; half++) {
            bf16x8 af[2], bfr[2];
            for (int i = 0; i < 2; i++) {
                int r = i * 16 + l16;
                int s = (half * 4 + quad + (r >> 1)) & 7;
                af[i] = *(const bf16x8*)&lA[r * 64 + s * 8];
            }
            for (int j = 0; j < 2; j++) {
                int r = wave * 32 + j * 16 + l16;
                int s = (half * 4 + quad + (r >> 1)) & 7;
                bfr[j] = *(const bf16x8*)&lB[r * 64 + s * 8];
            }
            for (int i = 0; i < 2; i++)
                for (int j = 0; j < 2; j++)
                    dacc[i][j] = __builtin_amdgcn_mfma_f32_16x16x32_bf16(af[i], bfr[j], dacc[i][j], 0, 0, 0);
        }
        __syncthreads();   // all waves done reading lA/lB before dls overwrite

        // softplus epilogue -> dls[p][dlocal] (aliased region)
        for (int j = 0; j < 2; j++) {
            int n = wave * 32 + j * 16 + l16;
            float bv = b2f(bdt[dblk * 128 + n]);
            for (int i = 0; i < 2; i++) {
                int mb = i * 16 + quad * 4;
                for (int vv = 0; vv < 4; vv++)
                    dls[(mb + vv) * 128 + n] = softplus_f(dacc[i][j][vv] + bv);
            }
        }
        __syncthreads();

        const float LOG2E = 1.4426950408889634f;
        float a_[8], h_[8];
        {
            u16x8 av = *(const u16x8*)&Alog[(size_t)d * 16 + nh * 8];
            u16x8 lv = *(const u16x8*)&latent[((size_t)bg * 2048 + d) * 16 + nh * 8];
            for (int n = 0; n < 8; n++) {
                a_[n] = -__expf(b2f(av[n])) * LOG2E;
                h_[n] = b2f(lv[n]);
            }
        }
        float Dd = b2f(Dp[d]);
        const int dll = wave * 32 + (lane & 31);

        u16 u_nx = u[(size_t)rowb * 2048 + d];
        u16 r_nx = xr[(size_t)rowb * 4096 + 2048 + d];
        #pragma unroll
        for (int p = 0; p < 32; p++) {
            float uu = b2f(u_nx), rsv = b2f(r_nx);
            if (p < 31) {
                u_nx = u[(size_t)(rowb + p + 1) * 2048 + d];
                r_nx = xr[(size_t)(rowb + p + 1) * 4096 + 2048 + d];
            }
            float dlt = dls[p * 128 + dll];
            float db  = dlt * uu;
            float y8 = 0.f;
            if (p == 0) {
                #pragma unroll
                for (int n = 0; n < 8; n++) {
                    h_[n] += db * Bs[0][nh * 8 + n];
                    y8 += h_[n] * Cs[0][nh * 8 + n];
                }
            } else {
                #pragma unroll
                for (int n = 0; n < 8; n++) {
                    float w = exp2f(dlt * a_[n]);
                    h_[n] = w * h_[n] + db * Bs[p][nh * 8 + n];
                    y8 += h_[n] * Cs[p][nh * 8 + n];
                }
            }
            float y = y8 + __shfl_xor(y8, 32);
            if (nh == 0)
                yg[(size_t)(rowb + p) * 2048 + d] = f2b((y + uu * Dd) * silu_f(rsv));
        }
    } else {
        float (*Ws)[16] = (float(*)[16])lsh;
        for (int i = tid; i < 768; i += 256) Ws[i >> 4][i & 15] = b2f(Wc[i]);
        __syncthreads();
        int gid = (bid - 1024) * 256 + tid;          // 126976 total
        int d = gid & 2047;
        int bi = gid >> 11;                          // b*31+i
        int b = bi / 31, i = bi - b * 31;
        const u16* lp = &latent[(((size_t)b * 32 + i) * 2048 + d) * 16];
        float lv[16];
        {
            u16x8 l0 = *(const u16x8*)lp, l1 = *(const u16x8*)(lp + 8);
            for (int m = 0; m < 8; m++) { lv[m] = b2f(l0[m]); lv[8 + m] = b2f(l1[m]); }
        }
        u16* outs[3] = {q, k, v};
        for (int pl = 0; pl < 3; pl++) {
            u16x8 o0, o1;
            for (int n = 0; n < 16; n++) {
                float s = 0.f;
                for (int m = 0; m < 16; m++) s += lv[m] * Ws[pl * 16 + n][m];
                if (n < 8) o0[n] = f2b(s); else o1[n - 8] = f2b(s);
            }
            u16* op = outs[pl] + (size_t)bi * 32768 + d * 16;
            *(u16x8*)op = o0; *(u16x8*)(op + 8) = o1;
        }
    }
}

// ---------------- fused: out-GEMM 128x64 split-K2 (blocks 0..511) + scores (512..2433) ----------------
// r6: bid decode with by fastest so same-A-panel blocks cluster per XCD.
__global__ __launch_bounds__(256) void gemm_scores_k(
    const u16* __restrict__ yg, const u16* __restrict__ Wout, float* __restrict__ out_part,
    const u16* __restrict__ q, const u16* __restrict__ kk, float* __restrict__ sc)
{
    int bid = blockIdx.x;
    if (bid < 512) {
        int by = bid & 15, bx = (bid >> 4) & 15, bz = bid >> 8;
        gemm_core<2, 64>(bx, by, bz, yg, Wout, 1024, 2048, 2048,
                         nullptr, out_part, 1024, 1024, (size_t)2048 * 1024);
        return;
    }
    int idx = bid - 512;             // b*961 + i*31 + j
    int b = idx / 961, r = idx - b * 961;
    int i = r / 31, j = r - i * 31;
    if (j > i) return;
    const u16* qp = q + ((size_t)b * 31 + i) * 32768;
    const u16* kp = kk + ((size_t)b * 31 + j) * 32768;
    float s = 0.f;
    for (int t = threadIdx.x * 8; t < 32768; t += 2048) {
        u16x8 a = *(const u16x8*)&qp[t];
        u16x8 c = *(const u16x8*)&kp[t];
        for (int e = 0; e < 8; e++) s += b2f(a[e]) * b2f(c[e]);
    }
    for (int off = 32; off; off >>= 1) s += __shfl_xor(s, off);
    __shared__ float red[4];
    if ((threadIdx.x & 63) == 0) red[threadIdx.x >> 6] = s;
    __syncthreads();
    if (threadIdx.x == 0)
        sc[idx] = (red[0] + red[1] + red[2] + red[3]) * 5.5242717e-3f; // 1/sqrt(32768)
}

// ---------------- fused epilogue: attv+softmax (0..1023) + redout KS=2 (1024..3071) ----------------
__global__ __launch_bounds__(256) void attv_redout_k(
    const float* __restrict__ sc, const u16* __restrict__ v,
    const float* __restrict__ part, void* __restrict__ dout,
    const u16* __restrict__ xraw)
{
    int flag = dtype_flag_block(xraw);
    int bid = blockIdx.x;
    if (bid < 1024) {
        int chunk = bid & 15, bi = bid >> 4;
        int b = bi >> 5, i = (bi & 31) - 1;   // i = -1 -> zero row (group 0)
        __shared__ float as[32];
        if (i >= 0 && threadIdx.x < 64) {
            float x = (threadIdx.x <= i) ? sc[(size_t)b * 961 + i * 31 + threadIdx.x] : -3.4e38f;
            float mx = x;
            for (int off = 32; off; off >>= 1) mx = fmaxf(mx, __shfl_xor(mx, off));
            float e = (threadIdx.x <= i) ? __expf(x - mx) : 0.f;
            float sm = e;
            for (int off = 32; off; off >>= 1) sm += __shfl_xor(sm, off);
            if (threadIdx.x < 32) as[threadIdx.x] = e / sm;
        }
        __syncthreads();
        int dn = chunk * 2048 + threadIdx.x * 8;
        float acc[8] = {0, 0, 0, 0, 0, 0, 0, 0};
        if (i >= 0) {
            for (int j = 0; j <= i; j++) {
                u16x8 vv = *(const u16x8*)&v[((size_t)b * 31 + j) * 32768 + dn];
                float aj = as[j];
                for (int e = 0; e < 8; e++) acc[e] += aj * b2f(vv[e]);
            }
            for (int e = 0; e < 8; e++) if (!(fabsf(acc[e]) < 1e30f)) acc[e] = 0.f;
        }
        size_t ofs = 2097152 + ((size_t)b * 32 + (i + 1)) * 32768 + dn;
        if (flag) {
            f32x4 o0, o1;
            for (int e = 0; e < 4; e++) { o0[e] = acc[e]; o1[e] = acc[4 + e]; }
            *(f32x4*)((float*)dout + ofs) = o0;
            *(f32x4*)((float*)dout + ofs + 4) = o1;
        } else {
            u16x8 o;
            for (int e = 0; e < 8; e++) o[e] = f2b(acc[e]);
            *(u16x8*)((u16*)dout + ofs) = o;
        }
    } else {
        int gid = (bid - 1024) * 256 + threadIdx.x;   // 524288 total
        int m = gid >> 8;
        int j = (gid & 255) * 4;
        f32x4 s = {0.f, 0.f, 0.f, 0.f};
        for (int ks = 0; ks < 2; ks++) {
            f32x4 p = *(const f32x4*)&part[((size_t)ks * 2048 + m) * 1024 + j];
            for (int e = 0; e < 4; e++) s[e] += p[e];
        }
        for (int e = 0; e < 4; e++) if (!(fabsf(s[e]) < 1e30f)) s[e] = 0.f;
        if (flag) {
            ((f32x4*)dout)[(size_t)m * 256 + (j >> 2)] = s;
        } else {
            u16x4 o;
            for (int e = 0; e < 4; e++) o[e] = f2b(s[e]);
            ((u16x4*)dout)[(size_t)m * 256 + (j >> 2)] = o;
        }
    }
}

extern "C" void kernel_launch(void* const* d_in, const int* in_sizes, int n_in,
                              void* d_out, int out_size, void* d_ws, size_t ws_size,
                              hipStream_t stream)
{
    char* ws = (char*)d_ws;
    const u16* xraw = (const u16*)d_in[0];
    // canonical bf16 inputs
    u16* cx    = (u16*)(ws + 0);
    u16* clat  = (u16*)(ws + 4194304);
    u16* cWin  = (u16*)(ws + 8388608);
    u16* ccw   = (u16*)(ws + 16777216);
    u16* ccb   = (u16*)(ws + 16793600);
    u16* wxp   = (u16*)(ws + 16797696);   // 128x2048 (W_x + zero pad)
    u16* cWdt  = (u16*)(ws + 17321984);
    u16* cbdt  = (u16*)(ws + 17584128);
    u16* cWout = (u16*)(ws + 17588224);
    u16* cAlog = (u16*)(ws + 21782528);
    u16* cD    = (u16*)(ws + 21848064);
    u16* cWc   = (u16*)(ws + 21852160);
    // intermediates
    float* xdf       = (float*)(ws + 21853760);  // 2048x128 f32 atomic accum (1MB)
    float* sc        = (float*)(ws + 39155264);  // 1922 f32
    u16*   u         = (u16*)(ws + 39163008);    // 2048x2048 bf16
    u16*   xr        = (u16*)(ws + 47551616);    // 2048x4096 bf16
    u16*   yg        = (u16*)(ws + 64328832);    // 2048x2048 bf16
    u16*   qb        = (u16*)(ws + 72717440);    // 3x 2031616 bf16
    u16*   kb        = qb + 2031616;
    u16*   vb        = kb + 2031616;
    float* out_part  = (float*)(ws + 84907136);  // 2x2048x1024 f32 (ends ~102 MB)

    // 1) canonicalize inputs to bf16 (+ zero the xdf atomic accumulator)
    CvtArgs ca;
    const void* srcs[14] = { d_in[0], d_in[1], d_in[2], d_in[3], d_in[4],
                             d_in[5], nullptr, d_in[6], d_in[7], d_in[8],
                             d_in[9], d_in[10], d_in[11], nullptr };
    u16* dsts[14] = { cx, clat, cWin, ccw, ccb,
                      wxp, wxp + 196608, cWdt, cbdt, cWout,
                      cAlog, cD, cWc, (u16*)xdf };
    int ns[14] = { 2097152, 2097152, 4194304, 8192, 2048,
                   196608, 65536, 131072, 2048, 2097152,
                   32768, 2048, 768, 524288 };
    int cum = 0;
    for (int i = 0; i < 14; i++) {
        ca.s[i] = srcs[i]; ca.d[i] = dsts[i];
        ca.cum[i] = cum; cum += ns[i] / 4;
    }
    ca.cum[14] = cum; ca.total = cum;    // 2,862,784 units
    cvt_all_k<<<(cum + 255) / 256, 256, 0, stream>>>(ca, xraw);

    // 2) xr = x @ W_in^T (M=2048,N=4096,K=1024), 128x64 tiles -> 1024 blocks
    gemm_bt<0, 64><<<dim3(64, 16, 1), 256, 0, stream>>>(cx, cWin, 1024, 1024, 1024,
                                                        xr, nullptr, 4096, 4096, 0);
    // 3) depthwise conv + SiLU
    conv_silu_k<<<2048, 256, 0, stream>>>(xr, ccw, ccb, u);
    // 4) x_dbl = u @ W_x^T, split-K 16 via atomicAdd -> xdf (pre-zeroed)
    gemm_bt<3, 64><<<dim3(2, 16, 16), 256, 0, stream>>>(u, wxp, 128, 2048, 2048,
                                                        nullptr, xdf, 128, 128, 0);
    // 5) scan n-split x2 + delta MFMA, 24KB LDS (0..1023) | qkv (1024..1519)
    scan_qkv_k<<<1520, 256, 0, stream>>>(u, xr, xdf, cWdt, cbdt, clat, cAlog, cD, yg,
                                         cWc, qb, kb, vb);
    // 6) out-GEMM 128x64 split-K2 (blocks 0..511) | scores (512..2433)
    gemm_scores_k<<<2434, 256, 0, stream>>>(yg, cWout, out_part, qb, kb, sc);
    // 7) attv+softmax -> d_out[2097152:] | split-K reduce -> d_out[0:2097152]
    attv_redout_k<<<3072, 256, 0, stream>>>(sc, vb, out_part, d_out, xraw);
}

// Round 9
// 224.470 us; speedup vs baseline: 1.0145x; 1.0145x over previous
//
#include <hip/hip_runtime.h>
#include <stdint.h>

typedef uint16_t u16;
typedef u16   u16x4  __attribute__((ext_vector_type(4)));
typedef u16   u16x8  __attribute__((ext_vector_type(8)));
typedef __bf16 bf16x8 __attribute__((ext_vector_type(8)));
typedef float f32x4  __attribute__((ext_vector_type(4)));

__device__ __forceinline__ float b2f(u16 x) {
    union { uint32_t u; float f; } c; c.u = ((uint32_t)x) << 16; return c.f;
}
__device__ __forceinline__ u16 f2b(float f) {
    union { float f; uint32_t u; } c; c.f = f;
    uint32_t r = c.u + 0x7FFFu + ((c.u >> 16) & 1u);
    return (u16)(r >> 16);
}
__device__ __forceinline__ float silu_f(float x) { return x / (1.f + __expf(-x)); }
__device__ __forceinline__ float softplus_f(float x) {
    return fmaxf(x, 0.f) + __logf(1.f + __expf(-fabsf(x)));
}

__device__ __forceinline__ void gload16(const u16* g, u16* l) {
    __builtin_amdgcn_global_load_lds(
        (const __attribute__((address_space(1))) void*)(g),
        (__attribute__((address_space(3))) void*)(l), 16, 0, 0);
}

// per-block dtype flag: 1 = f32 inputs, 0 = bf16. Contains barriers; call first.
__device__ __forceinline__ int dtype_flag_block(const u16* __restrict__ xraw) {
    __shared__ int bad;
    if (threadIdx.x == 0) bad = 0;
    __syncthreads();
    float v = b2f(xraw[threadIdx.x]);
    if (!(fabsf(v) < 1000.f)) atomicAdd(&bad, 1);   // NaN-safe
    __syncthreads();
    return bad;
}

// ---------------- unified input canonicalization (13 segments) ----------------
struct CvtArgs {
    const void* s[13];
    u16* d[13];
    int cum[14];
    int total;
};
__global__ __launch_bounds__(256) void cvt_all_k(CvtArgs a, const u16* __restrict__ xraw)
{
    int flag = dtype_flag_block(xraw);
    int u4 = blockIdx.x * 256 + threadIdx.x;
    if (u4 >= a.total) return;
    int seg = 0;
    while (u4 >= a.cum[seg + 1]) seg++;
    int local = u4 - a.cum[seg];
    const void* s = a.s[seg];
    u16x4 o;
    if (s == nullptr) {
        o[0] = o[1] = o[2] = o[3] = 0;
    } else if (flag) {
        f32x4 vv = ((const f32x4*)s)[local];
        for (int e = 0; e < 4; e++) o[e] = f2b(vv[e]);
    } else {
        o = ((const u16x4*)s)[local];
    }
    *(u16x4*)(a.d[seg] + (size_t)local * 4) = o;
}

// ---------------- MFMA NT GEMM core: C[m,n] = sum_k A[m,k]*B[n,k] ----------------
// 128(M) x TN(N) tile, BK=64, 4 waves (2x2), swizzled LDS slots.
// Async global_load_lds staging. EPI 0: bf16 store. 2: f32 partial at
// Cf + z*zslab. Kc multiple of 64.
// NOTE r2: TN=128 on the *mixed-grid* out-GEMM regressed (1 blk/CU tail
// behind score blocks). r9: testing TN=128 on the standalone xr GEMM only.
template<int EPI, int TN>
__device__ __forceinline__ void gemm_core(
    int bx, int by, int bz,
    const u16* __restrict__ A, const u16* __restrict__ B,
    int Kc, int lda, int ldb,
    u16* __restrict__ Cb, float* __restrict__ Cf, int ldc, int ncols,
    size_t zslab)
{
    constexpr int NJ = TN / 32;
    constexpr int BT = TN / 32;
    __shared__ __align__(16) u16 lA[128 * 64];
    __shared__ __align__(16) u16 lB[TN * 64];
    const int tid  = threadIdx.x;
    const int wave = tid >> 6, lane = tid & 63;
    const int quad = lane >> 4, l16 = lane & 15;
    const int wm = wave & 1, wn = wave >> 1;
    const int row0 = by * 128, col0 = bx * TN;
    const int kbeg = bz * Kc;

    f32x4 acc[4][NJ];
    const f32x4 zf = {0.f, 0.f, 0.f, 0.f};
    for (int i = 0; i < 4; i++) for (int j = 0; j < NJ; j++) acc[i][j] = zf;

    // chunk c: 16B at lX[c*8]; row r=c>>3, slot s=c&7 holds k-group
    // q=(s-(r>>1))&7 (bank swizzle).
    const u16* Ap[4]; const u16* Bp[BT];
    int lbaseA[4], lbaseB[BT];
    for (int t = 0; t < 4; t++) {
        int c = t * 256 + tid;
        int r = c >> 3, s = c & 7;
        int q = (s - (r >> 1)) & 7;
        Ap[t] = A + (size_t)(row0 + r) * lda + q * 8 + kbeg;
        lbaseA[t] = (t * 256 + wave * 64) * 8;
    }
    for (int t = 0; t < BT; t++) {
        int c = t * 256 + tid;
        int r = c >> 3, s = c & 7;
        int q = (s - (r >> 1)) & 7;
        Bp[t] = B + (size_t)(col0 + r) * ldb + q * 8 + kbeg;
        lbaseB[t] = (t * 256 + wave * 64) * 8;
    }

    for (int k0 = 0; k0 < Kc; k0 += 64) {
        for (int t = 0; t < 4; t++) gload16(Ap[t] + k0, &lA[lbaseA[t]]);
        for (int t = 0; t < BT; t++) gload16(Bp[t] + k0, &lB[lbaseB[t]]);
        __syncthreads();
        for (int half = 0; half < 2; half++) {
            bf16x8 af[4], bfr[NJ];
            for (int i = 0; i < 4; i++) {
                int r = wm * 64 + i * 16 + l16;
                int s = (half * 4 + quad + (r >> 1)) & 7;
                af[i] = *(const bf16x8*)&lA[r * 64 + s * 8];
            }
            for (int j = 0; j < NJ; j++) {
                int r = wn * (TN / 2) + j * 16 + l16;
                int s = (half * 4 + quad + (r >> 1)) & 7;
                bfr[j] = *(const bf16x8*)&lB[r * 64 + s * 8];
            }
            for (int i = 0; i < 4; i++)
                for (int j = 0; j < NJ; j++)
                    acc[i][j] = __builtin_amdgcn_mfma_f32_16x16x32_bf16(af[i], bfr[j], acc[i][j], 0, 0, 0);
        }
        __syncthreads();
    }

    float* dstf = (EPI == 2) ? (Cf + (size_t)bz * zslab) : Cf;
    for (int i = 0; i < 4; i++) {
        int mb = row0 + wm * 64 + i * 16 + quad * 4;
        for (int j = 0; j < NJ; j++) {
            int n = col0 + wn * (TN / 2) + j * 16 + l16;
            if (n >= ncols) continue;
            if (EPI == 0) {
                for (int v = 0; v < 4; v++)
                    Cb[(size_t)(mb + v) * ldc + n] = f2b(acc[i][j][v]);
            } else {
                for (int v = 0; v < 4; v++)
                    dstf[(size_t)(mb + v) * ldc + n] = acc[i][j][v];
            }
        }
    }
}

template<int EPI, int TN>
__global__ __launch_bounds__(256) void gemm_bt(
    const u16* __restrict__ A, const u16* __restrict__ B,
    int Kc, int lda, int ldb,
    u16* __restrict__ Cb, float* __restrict__ Cf, int ldc, int ncols,
    size_t zslab)
{
    gemm_core<EPI, TN>(blockIdx.x, blockIdx.y, blockIdx.z,
                       A, B, Kc, lda, ldb, Cb, Cf, ldc, ncols, zslab);
}

// reduce 16 x_dbl split-K f32 slabs -> bf16 xdbl (2048 x 128)
__global__ __launch_bounds__(256) void redc_k(
    const float* __restrict__ part, u16* __restrict__ dst)
{
    int gid = blockIdx.x * 256 + threadIdx.x;   // 65536 total
    int idx = gid * 4;
    f32x4 s = {0.f, 0.f, 0.f, 0.f};
    for (int sl = 0; sl < 16; sl++) {
        f32x4 p = *(const f32x4*)&part[(size_t)sl * 262144 + idx];
        for (int e = 0; e < 4; e++) s[e] += p[e];
    }
    u16x4 o;
    for (int e = 0; e < 4; e++) o[e] = f2b(s[e]);
    *(u16x4*)&dst[idx] = o;
}

// ---------------- depthwise causal conv(4) + bias + SiLU ----------------
__global__ __launch_bounds__(256) void conv_silu_k(
    const u16* __restrict__ xr, const u16* __restrict__ cw,
    const u16* __restrict__ cb, u16* __restrict__ u)
{
    int tid = threadIdx.x;
    int bl  = blockIdx.x;       // b*1024 + l
    int l   = bl & 1023;
    int d0  = tid * 8;
    float acc[8];
    u16x8 bias = *(const u16x8*)&cb[d0];
    for (int j = 0; j < 8; j++) acc[j] = b2f(bias[j]);
    union { u16x8 v[4]; u16 s[32]; } wb;
    for (int t = 0; t < 4; t++) wb.v[t] = *(const u16x8*)&cw[d0 * 4 + t * 8];
    for (int t = 0; t < 4; t++) {
        int ls = l - 3 + t;
        if (ls < 0) continue;
        u16x8 xv = *(const u16x8*)&xr[(size_t)(bl - 3 + t) * 4096 + d0];
        for (int j = 0; j < 8; j++) acc[j] += b2f(xv[j]) * b2f(wb.s[j * 4 + t]);
    }
    u16x8 o;
    for (int j = 0; j < 8; j++) o[j] = f2b(silu_f(acc[j]));
    *(u16x8*)&u[(size_t)bl * 2048 + d0] = o;
}

// ---------------- fused: scan (blocks 0..1023) + qkv (1024..1519) ----------------
// r6 structure (best measured): n-split x2 scan + delta MFMA + LDS aliasing.
// LDS 24KB => 6 blocks/CU. u16 units: lA[0,2048) | lB[2048,10240) |
// Bs[10240,11264) | Cs[11264,12288); phase2: dls f32 aliases [0,8192).
__global__ __launch_bounds__(256) void scan_qkv_k(
    const u16* __restrict__ u, const u16* __restrict__ xr,
    const u16* __restrict__ xdbl, const u16* __restrict__ Wdt,
    const u16* __restrict__ bdt,
    const u16* __restrict__ latent, const u16* __restrict__ Alog,
    const u16* __restrict__ Dp, u16* __restrict__ yg,
    const u16* __restrict__ Wc, u16* __restrict__ q, u16* __restrict__ k,
    u16* __restrict__ v)
{
    __shared__ __align__(16) u16 lsh[12288];    // 24KB
    int tid = threadIdx.x;
    int bid = blockIdx.x;
    if (bid < 1024) {
        u16* lA = lsh;
        u16* lB = lsh + 2048;
        float* dls = (float*)lsh;               // [32][128], aliases lA+lB
        float (*Bs)[16] = (float(*)[16])(lsh + 10240);
        float (*Cs)[16] = (float(*)[16])(lsh + 11264);
        const int wave = tid >> 6, lane = tid & 63;
        const int quad = lane >> 4, l16 = lane & 15;
        const int nh = lane >> 5;
        int dblk = bid & 15, bg = bid >> 4;      // bg = b*32+g
        const int d = dblk * 128 + wave * 32 + (lane & 31);
        const int rowb = bg * 32;

        // stage A = xdbl[bg's 32 rows][0:64] (swizzled chunks, 1/thread)
        {
            int r = tid >> 3, s = tid & 7;
            int qg = (s - (r >> 1)) & 7;
            gload16(&xdbl[(size_t)(rowb + r) * 128 + qg * 8], &lA[(wave * 64) * 8]);
        }
        // stage B = Wdt rows [dblk*128, +128) (4 chunks/thread)
        for (int t = 0; t < 4; t++) {
            int c = t * 256 + tid;
            int r = c >> 3, s = c & 7;
            int qg = (s - (r >> 1)) & 7;
            gload16(&Wdt[(size_t)(dblk * 128 + r) * 64 + qg * 8],
                    &lB[(t * 256 + wave * 64) * 8]);
        }
        // B/C tiles from xdbl cols 64..96
        for (int idx = tid; idx < 512; idx += 256) {
            int p = idx >> 4, n = idx & 15;
            const u16* xp = &xdbl[(size_t)(rowb + p) * 128];
            Bs[p][n] = b2f(xp[64 + n]);
            Cs[p][n] = b2f(xp[80 + n]);
        }
        __syncthreads();

        // delta MFMA: C[32p x 128d], wave covers 32 d-cols: 2 p-sub x 2 d-sub
        f32x4 dacc[2][2];
        const f32x4 zf = {0.f, 0.f, 0.f, 0.f};
        for (int i = 0; i < 2; i++) for (int j = 0; j < 2; j++) dacc[i][j] = zf;
        for (int half = 0; half < 2; half++) {
            bf16x8 af[2], bfr[2];
            for (int i = 0; i < 2; i++) {
                int r = i * 16 + l16;
                int s = (half * 4 + quad + (r >> 1)) & 7;
                af[i] = *(const bf16x8*)&lA[r * 64 + s * 8];
            }
            for (int j = 0; j < 2; j++) {
                int r = wave * 32 + j * 16 + l16;
                int s = (half * 4 + quad + (r >> 1)) & 7;
                bfr[j] = *(const bf16x8*)&lB[r * 64 + s * 8];
            }
            for (int i = 0; i < 2; i++)
                for (int j = 0; j < 2; j++)
                    dacc[i][j] = __builtin_amdgcn_mfma_f32_16x16x32_bf16(af[i], bfr[j], dacc[i][j], 0, 0, 0);
        }
        __syncthreads();   // all waves done reading lA/lB before dls overwrite

        // softplus epilogue -> dls[p][dlocal] (aliased region)
        for (int j = 0; j < 2; j++) {
            int n = wave * 32 + j * 16 + l16;
            float bv = b2f(bdt[dblk * 128 + n]);
            for (int i = 0; i < 2; i++) {
                int mb = i * 16 + quad * 4;
                for (int vv = 0; vv < 4; vv++)
                    dls[(mb + vv) * 128 + n] = softplus_f(dacc[i][j][vv] + bv);
            }
        }
        __syncthreads();

        const float LOG2E = 1.4426950408889634f;
        float a_[8], h_[8];
        {
            u16x8 av = *(const u16x8*)&Alog[(size_t)d * 16 + nh * 8];
            u16x8 lv = *(const u16x8*)&latent[((size_t)bg * 2048 + d) * 16 + nh * 8];
            for (int n = 0; n < 8; n++) {
                a_[n] = -__expf(b2f(av[n])) * LOG2E;
                h_[n] = b2f(lv[n]);
            }
        }
        float Dd = b2f(Dp[d]);
        const int dll = wave * 32 + (lane & 31);

        u16 u_nx = u[(size_t)rowb * 2048 + d];
        u16 r_nx = xr[(size_t)rowb * 4096 + 2048 + d];
        #pragma unroll
        for (int p = 0; p < 32; p++) {
            float uu = b2f(u_nx), rsv = b2f(r_nx);
            if (p < 31) {
                u_nx = u[(size_t)(rowb + p + 1) * 2048 + d];
                r_nx = xr[(size_t)(rowb + p + 1) * 4096 + 2048 + d];
            }
            float dlt = dls[p * 128 + dll];
            float db  = dlt * uu;
            float y8 = 0.f;
            if (p == 0) {
                #pragma unroll
                for (int n = 0; n < 8; n++) {
                    h_[n] += db * Bs[0][nh * 8 + n];
                    y8 += h_[n] * Cs[0][nh * 8 + n];
                }
            } else {
                #pragma unroll
                for (int n = 0; n < 8; n++) {
                    float w = exp2f(dlt * a_[n]);
                    h_[n] = w * h_[n] + db * Bs[p][nh * 8 + n];
                    y8 += h_[n] * Cs[p][nh * 8 + n];
                }
            }
            float y = y8 + __shfl_xor(y8, 32);
            if (nh == 0)
                yg[(size_t)(rowb + p) * 2048 + d] = f2b((y + uu * Dd) * silu_f(rsv));
        }
    } else {
        float (*Ws)[16] = (float(*)[16])lsh;
        for (int i = tid; i < 768; i += 256) Ws[i >> 4][i & 15] = b2f(Wc[i]);
        __syncthreads();
        int gid = (bid - 1024) * 256 + tid;          // 126976 total
        int d = gid & 2047;
        int bi = gid >> 11;                          // b*31+i
        int b = bi / 31, i = bi - b * 31;
        const u16* lp = &latent[(((size_t)b * 32 + i) * 2048 + d) * 16];
        float lv[16];
        {
            u16x8 l0 = *(const u16x8*)lp, l1 = *(const u16x8*)(lp + 8);
            for (int m = 0; m < 8; m++) { lv[m] = b2f(l0[m]); lv[8 + m] = b2f(l1[m]); }
        }
        u16* outs[3] = {q, k, v};
        for (int pl = 0; pl < 3; pl++) {
            u16x8 o0, o1;
            for (int n = 0; n < 16; n++) {
                float s = 0.f;
                for (int m = 0; m < 16; m++) s += lv[m] * Ws[pl * 16 + n][m];
                if (n < 8) o0[n] = f2b(s); else o1[n - 8] = f2b(s);
            }
            u16* op = outs[pl] + (size_t)bi * 32768 + d * 16;
            *(u16x8*)op = o0; *(u16x8*)(op + 8) = o1;
        }
    }
}

// ---------------- fused: out-GEMM 128x64 split-K2 (blocks 0..511) + scores (512..2433) ----------------
// by-fastest decode so same-A-panel blocks cluster per XCD.
__global__ __launch_bounds__(256) void gemm_scores_k(
    const u16* __restrict__ yg, const u16* __restrict__ Wout, float* __restrict__ out_part,
    const u16* __restrict__ q, const u16* __restrict__ kk, float* __restrict__ sc)
{
    int bid = blockIdx.x;
    if (bid < 512) {
        int by = bid & 15, bx = (bid >> 4) & 15, bz = bid >> 8;
        gemm_core<2, 64>(bx, by, bz, yg, Wout, 1024, 2048, 2048,
                         nullptr, out_part, 1024, 1024, (size_t)2048 * 1024);
        return;
    }
    int idx = bid - 512;             // b*961 + i*31 + j
    int b = idx / 961, r = idx - b * 961;
    int i = r / 31, j = r - i * 31;
    if (j > i) return;
    const u16* qp = q + ((size_t)b * 31 + i) * 32768;
    const u16* kp = kk + ((size_t)b * 31 + j) * 32768;
    float s = 0.f;
    for (int t = threadIdx.x * 8; t < 32768; t += 2048) {
        u16x8 a = *(const u16x8*)&qp[t];
        u16x8 c = *(const u16x8*)&kp[t];
        for (int e = 0; e < 8; e++) s += b2f(a[e]) * b2f(c[e]);
    }
    for (int off = 32; off; off >>= 1) s += __shfl_xor(s, off);
    __shared__ float red[4];
    if ((threadIdx.x & 63) == 0) red[threadIdx.x >> 6] = s;
    __syncthreads();
    if (threadIdx.x == 0)
        sc[idx] = (red[0] + red[1] + red[2] + red[3]) * 5.5242717e-3f; // 1/sqrt(32768)
}

// ---------------- fused epilogue: attv+softmax (0..1023) + redout KS=2 (1024..3071) ----------------
__global__ __launch_bounds__(256) void attv_redout_k(
    const float* __restrict__ sc, const u16* __restrict__ v,
    const float* __restrict__ part, void* __restrict__ dout,
    const u16* __restrict__ xraw)
{
    int flag = dtype_flag_block(xraw);
    int bid = blockIdx.x;
    if (bid < 1024) {
        int chunk = bid & 15, bi = bid >> 4;
        int b = bi >> 5, i = (bi & 31) - 1;   // i = -1 -> zero row (group 0)
        __shared__ float as[32];
        if (i >= 0 && threadIdx.x < 64) {
            float x = (threadIdx.x <= i) ? sc[(size_t)b * 961 + i * 31 + threadIdx.x] : -3.4e38f;
            float mx = x;
            for (int off = 32; off; off >>= 1) mx = fmaxf(mx, __shfl_xor(mx, off));
            float e = (threadIdx.x <= i) ? __expf(x - mx) : 0.f;
            float sm = e;
            for (int off = 32; off; off >>= 1) sm += __shfl_xor(sm, off);
            if (threadIdx.x < 32) as[threadIdx.x] = e / sm;
        }
        __syncthreads();
        int dn = chunk * 2048 + threadIdx.x * 8;
        float acc[8] = {0, 0, 0, 0, 0, 0, 0, 0};
        if (i >= 0) {
            for (int j = 0; j <= i; j++) {
                u16x8 vv = *(const u16x8*)&v[((size_t)b * 31 + j) * 32768 + dn];
                float aj = as[j];
                for (int e = 0; e < 8; e++) acc[e] += aj * b2f(vv[e]);
            }
            for (int e = 0; e < 8; e++) if (!(fabsf(acc[e]) < 1e30f)) acc[e] = 0.f;
        }
        size_t ofs = 2097152 + ((size_t)b * 32 + (i + 1)) * 32768 + dn;
        if (flag) {
            f32x4 o0, o1;
            for (int e = 0; e < 4; e++) { o0[e] = acc[e]; o1[e] = acc[4 + e]; }
            *(f32x4*)((float*)dout + ofs) = o0;
            *(f32x4*)((float*)dout + ofs + 4) = o1;
        } else {
            u16x8 o;
            for (int e = 0; e < 8; e++) o[e] = f2b(acc[e]);
            *(u16x8*)((u16*)dout + ofs) = o;
        }
    } else {
        int gid = (bid - 1024) * 256 + threadIdx.x;   // 524288 total
        int m = gid >> 8;
        int j = (gid & 255) * 4;
        f32x4 s = {0.f, 0.f, 0.f, 0.f};
        for (int ks = 0; ks < 2; ks++) {
            f32x4 p = *(const f32x4*)&part[((size_t)ks * 2048 + m) * 1024 + j];
            for (int e = 0; e < 4; e++) s[e] += p[e];
        }
        for (int e = 0; e < 4; e++) if (!(fabsf(s[e]) < 1e30f)) s[e] = 0.f;
        if (flag) {
            ((f32x4*)dout)[(size_t)m * 256 + (j >> 2)] = s;
        } else {
            u16x4 o;
            for (int e = 0; e < 4; e++) o[e] = f2b(s[e]);
            ((u16x4*)dout)[(size_t)m * 256 + (j >> 2)] = o;
        }
    }
}

extern "C" void kernel_launch(void* const* d_in, const int* in_sizes, int n_in,
                              void* d_out, int out_size, void* d_ws, size_t ws_size,
                              hipStream_t stream)
{
    char* ws = (char*)d_ws;
    const u16* xraw = (const u16*)d_in[0];
    // canonical bf16 inputs
    u16* cx    = (u16*)(ws + 0);
    u16* clat  = (u16*)(ws + 4194304);
    u16* cWin  = (u16*)(ws + 8388608);
    u16* ccw   = (u16*)(ws + 16777216);
    u16* ccb   = (u16*)(ws + 16793600);
    u16* wxp   = (u16*)(ws + 16797696);   // 128x2048 (W_x + zero pad)
    u16* cWdt  = (u16*)(ws + 17321984);
    u16* cbdt  = (u16*)(ws + 17584128);
    u16* cWout = (u16*)(ws + 17588224);
    u16* cAlog = (u16*)(ws + 21782528);
    u16* cD    = (u16*)(ws + 21848064);
    u16* cWc   = (u16*)(ws + 21852160);
    // intermediates (private; ws ~268 MB)
    float* xdbl_part = (float*)(ws + 21853760);  // 16 x 2048x128 f32 slabs
    u16*   xdbl      = (u16*)(ws + 38630976);    // 2048x128 bf16 (reduced)
    float* sc        = (float*)(ws + 39155264);  // 1922 f32
    u16*   u         = (u16*)(ws + 39163008);    // 2048x2048 bf16
    u16*   xr        = (u16*)(ws + 47551616);    // 2048x4096 bf16
    u16*   yg        = (u16*)(ws + 64328832);    // 2048x2048 bf16
    u16*   qb        = (u16*)(ws + 72717440);    // 3x 2031616 bf16
    u16*   kb        = qb + 2031616;
    u16*   vb        = kb + 2031616;
    float* out_part  = (float*)(ws + 84907136);  // 2x2048x1024 f32 (ends ~102 MB)

    // 1) canonicalize inputs to bf16
    CvtArgs ca;
    const void* srcs[13] = { d_in[0], d_in[1], d_in[2], d_in[3], d_in[4],
                             d_in[5], nullptr, d_in[6], d_in[7], d_in[8],
                             d_in[9], d_in[10], d_in[11] };
    u16* dsts[13] = { cx, clat, cWin, ccw, ccb,
                      wxp, wxp + 196608, cWdt, cbdt, cWout,
                      cAlog, cD, cWc };
    int ns[13] = { 2097152, 2097152, 4194304, 8192, 2048,
                   196608, 65536, 131072, 2048, 2097152,
                   32768, 2048, 768 };
    int cum = 0;
    for (int i = 0; i < 13; i++) {
        ca.s[i] = srcs[i]; ca.d[i] = dsts[i];
        ca.cum[i] = cum; cum += ns[i] / 4;
    }
    ca.cum[13] = cum; ca.total = cum;    // 2,731,712 units
    cvt_all_k<<<(cum + 255) / 256, 256, 0, stream>>>(ca, xraw);

    // 2) xr = x @ W_in^T (M=2048,N=4096,K=1024), 128x128 tiles -> 512 blocks
    //    r9 single-variable test: TN=128 on the standalone xr GEMM only.
    gemm_bt<0, 128><<<dim3(32, 16, 1), 256, 0, stream>>>(cx, cWin, 1024, 1024, 1024,
                                                         xr, nullptr, 4096, 4096, 0);
    // 3) depthwise conv + SiLU
    conv_silu_k<<<2048, 256, 0, stream>>>(xr, ccw, ccb, u);
    // 4) x_dbl = u @ W_x^T, split-K 16 -> f32 slabs, 128x64 tiles -> 512 blocks
    gemm_bt<2, 64><<<dim3(2, 16, 16), 256, 0, stream>>>(u, wxp, 128, 2048, 2048,
                                                        nullptr, xdbl_part, 128, 128,
                                                        262144);
    // 5) reduce 16 slabs -> xdbl bf16 (2048x128)
    redc_k<<<256, 256, 0, stream>>>(xdbl_part, xdbl);
    // 6) scan n-split x2 + delta MFMA, 24KB LDS (blocks 0..1023) | qkv (1024..1519)
    scan_qkv_k<<<1520, 256, 0, stream>>>(u, xr, xdbl, cWdt, cbdt, clat, cAlog, cD, yg,
                                         cWc, qb, kb, vb);
    // 7) out-GEMM 128x64 split-K2 (blocks 0..511) | scores (512..2433)
    gemm_scores_k<<<2434, 256, 0, stream>>>(yg, cWout, out_part, qb, kb, sc);
    // 8) attv+softmax -> d_out[2097152:] | split-K reduce -> d_out[0:2097152]
    attv_redout_k<<<3072, 256, 0, stream>>>(sc, vb, out_part, d_out, xraw);
}